// Round 6
// baseline (142.512 us; speedup 1.0000x reference)
//
#include <hip/hip_runtime.h>
#include <hip/hip_bf16.h>

#define N_    16
#define V_    5023
#define F_    9976
#define HW_   (512*512)
#define NV_   (N_*V_)      // 80368
#define NF_   (N_*F_)      // 159616
#define NPIX_ (N_*HW_)     // 4194304
#define MMB_  64           // minmax partial blocks

// native clang vectors — required by __builtin_nontemporal_* (HIP float4 is a struct)
typedef float f32x4 __attribute__((ext_vector_type(4)));
typedef int   i32x4 __attribute__((ext_vector_type(4)));

// ---- ordered-float <-> uint encoding (monotone over all finite floats) ----
__device__ __forceinline__ unsigned int encf(float f) {
    unsigned int b = __float_as_uint(f);
    return (b & 0x80000000u) ? ~b : (b | 0x80000000u);
}
__device__ __forceinline__ float decf(unsigned int e) {
    unsigned int b = (e & 0x80000000u) ? (e & 0x7FFFFFFFu) : ~e;
    return __uint_as_float(b);
}

// Kernel 1: per-block min/max partials over tv[:,:,2].
__global__ __launch_bounds__(256) void minmax_kernel(
        const float* __restrict__ tv, uint2* __restrict__ partial) {
    float vmin = 1e30f, vmax = -1e30f;
    for (int i = blockIdx.x * 256 + threadIdx.x; i < NV_; i += MMB_ * 256) {
        float z = tv[3*i + 2];
        vmin = fminf(vmin, z);
        vmax = fmaxf(vmax, z);
    }
#pragma unroll
    for (int off = 32; off > 0; off >>= 1) {
        vmin = fminf(vmin, __shfl_down(vmin, off));
        vmax = fmaxf(vmax, __shfl_down(vmax, off));
    }
    __shared__ float smin[4], smax[4];
    const int lane = threadIdx.x & 63, w = threadIdx.x >> 6;
    if (lane == 0) { smin[w] = vmin; smax[w] = vmax; }
    __syncthreads();
    if (threadIdx.x == 0) {
        float m = fminf(fminf(smin[0], smin[1]), fminf(smin[2], smin[3]));
        float M = fmaxf(fmaxf(smax[0], smax[1]), fmaxf(smax[2], smax[3]));
        partial[blockIdx.x] = make_uint2(encf(M), encf(m));
    }
}

// Kernel 2: redundant 64-wide reduce of partials, then build
// face_attr[n*F+f] = {zval(v0), zval(v1), zval(v2), 0}. Table 2.55 MB.
__global__ __launch_bounds__(256) void table_kernel(
        const float* __restrict__ tv, const int* __restrict__ faces,
        const uint2* __restrict__ partial, f32x4* __restrict__ table) {
    __shared__ float s_zmax, s_inv;
    if (threadIdx.x < 64) {
        uint2 p = partial[threadIdx.x];            // MMB_ == 64 == wave width
        unsigned int eM = p.x, em = p.y;
#pragma unroll
        for (int off = 32; off > 0; off >>= 1) {
            eM = max(eM, (unsigned int)__shfl_down((int)eM, off));
            em = min(em, (unsigned int)__shfl_down((int)em, off));
        }
        if (threadIdx.x == 0) {
            float zmax = decf(eM);
            s_zmax = zmax;
            s_inv  = 1.0f / (zmax - decf(em));
        }
    }
    __syncthreads();
    const int f = blockIdx.x * 256 + threadIdx.x;
    if (f >= F_) return;
    const int n = blockIdx.y;
    const float zmax = s_zmax, inv = s_inv;
    const int v0 = faces[3*f], v1 = faces[3*f + 1], v2 = faces[3*f + 2];
    const float* base = tv + n * (V_ * 3);
    f32x4 o;
    o.x = (zmax - base[3*v0 + 2]) * inv;
    o.y = (zmax - base[3*v1 + 2]) * inv;
    o.z = (zmax - base[3*v2 + 2]) * inv;
    o.w = 0.0f;
    table[n * F_ + f] = o;
}

// Kernel 3: render, 8 pixels/thread. nt streams (p2f/bary/out) keep the table
// L2-resident; gathers are PREDICATED (exec-masked) so the ~30% invalid
// pixels issue no memory transaction — R5 showed unconditional gathers
// regress 8 µs. 8 independent gathers/thread for latency hiding.
__global__ __launch_bounds__(256) void render_kernel(
        const int*    __restrict__ p2f,    // (NPIX) int32
        const float*  __restrict__ bary,   // (NPIX,3) f32
        const f32x4*  __restrict__ table,  // (N*F) f32x4
        float*        __restrict__ out) {  // (NPIX) f32
    const int t = blockIdx.x * 256 + threadIdx.x;   // pixels 8t .. 8t+7
    const i32x4 pp0 = __builtin_nontemporal_load((const i32x4*)p2f + 2*t + 0);
    const i32x4 pp1 = __builtin_nontemporal_load((const i32x4*)p2f + 2*t + 1);
    const f32x4 ba0 = __builtin_nontemporal_load((const f32x4*)bary + 6*t + 0);
    const f32x4 ba1 = __builtin_nontemporal_load((const f32x4*)bary + 6*t + 1);
    const f32x4 ba2 = __builtin_nontemporal_load((const f32x4*)bary + 6*t + 2);
    const f32x4 ba3 = __builtin_nontemporal_load((const f32x4*)bary + 6*t + 3);
    const f32x4 ba4 = __builtin_nontemporal_load((const f32x4*)bary + 6*t + 4);
    const f32x4 ba5 = __builtin_nontemporal_load((const f32x4*)bary + 6*t + 5);

    f32x4 o0 = {0.f, 0.f, 0.f, 0.f};
    f32x4 o1 = {0.f, 0.f, 0.f, 0.f};
    if (pp0.x >= 0) { const f32x4 a = table[pp0.x];
        o0.x = ba0.x * a.x + ba0.y * a.y + ba0.z * a.z; }
    if (pp0.y >= 0) { const f32x4 a = table[pp0.y];
        o0.y = ba0.w * a.x + ba1.x * a.y + ba1.y * a.z; }
    if (pp0.z >= 0) { const f32x4 a = table[pp0.z];
        o0.z = ba1.z * a.x + ba1.w * a.y + ba2.x * a.z; }
    if (pp0.w >= 0) { const f32x4 a = table[pp0.w];
        o0.w = ba2.y * a.x + ba2.z * a.y + ba2.w * a.z; }
    if (pp1.x >= 0) { const f32x4 a = table[pp1.x];
        o1.x = ba3.x * a.x + ba3.y * a.y + ba3.z * a.z; }
    if (pp1.y >= 0) { const f32x4 a = table[pp1.y];
        o1.y = ba3.w * a.x + ba4.x * a.y + ba4.y * a.z; }
    if (pp1.z >= 0) { const f32x4 a = table[pp1.z];
        o1.z = ba4.z * a.x + ba4.w * a.y + ba5.x * a.z; }
    if (pp1.w >= 0) { const f32x4 a = table[pp1.w];
        o1.w = ba5.y * a.x + ba5.z * a.y + ba5.w * a.z; }

    __builtin_nontemporal_store(o0, (f32x4*)out + 2*t + 0);
    __builtin_nontemporal_store(o1, (f32x4*)out + 2*t + 1);
}

extern "C" void kernel_launch(void* const* d_in, const int* in_sizes, int n_in,
                              void* d_out, int out_size, void* d_ws, size_t ws_size,
                              hipStream_t stream) {
    const float* tv    = (const float*)d_in[0];  // f32 (N,V,3)
    const float* bary  = (const float*)d_in[1];  // f32 (N,H,W,1,3)
    const int*   faces = (const int*)d_in[2];    // int32 (F,3)
    const int*   p2f   = (const int*)d_in[3];    // int32 (N,H,W,1)
    float* outp = (float*)d_out;

    uint2* partial = (uint2*)d_ws;                     // 64 * 8 B
    f32x4* table   = (f32x4*)((char*)d_ws + 1024);     // 2.55 MB, 16B-aligned

    minmax_kernel<<<MMB_, 256, 0, stream>>>(tv, partial);
    dim3 tgrid((F_ + 255) / 256, N_);
    table_kernel<<<tgrid, 256, 0, stream>>>(tv, faces, partial, table);
    render_kernel<<<NPIX_ / 8 / 256, 256, 0, stream>>>(p2f, bary, table, outp);
}

// Round 7
// 122.080 us; speedup vs baseline: 1.1674x; 1.1674x over previous
//
#include <hip/hip_runtime.h>
#include <hip/hip_bf16.h>

#define N_    16
#define V_    5023
#define F_    9976
#define HW_   (512*512)
#define NV_   (N_*V_)      // 80368
#define NF_   (N_*F_)      // 159616
#define NPIX_ (N_*HW_)     // 4194304
#define MMB_  64           // minmax partial blocks

// native clang vectors — required by __builtin_nontemporal_* (HIP float4 is a struct)
typedef float f32x4 __attribute__((ext_vector_type(4)));
typedef int   i32x4 __attribute__((ext_vector_type(4)));

// ---- ordered-float <-> uint encoding (monotone over all finite floats) ----
__device__ __forceinline__ unsigned int encf(float f) {
    unsigned int b = __float_as_uint(f);
    return (b & 0x80000000u) ? ~b : (b | 0x80000000u);
}
__device__ __forceinline__ float decf(unsigned int e) {
    unsigned int b = (e & 0x80000000u) ? (e & 0x7FFFFFFFu) : ~e;
    return __uint_as_float(b);
}

// Kernel 1: per-block min/max partials over tv[:,:,2].
__global__ __launch_bounds__(256) void minmax_kernel(
        const float* __restrict__ tv, uint2* __restrict__ partial) {
    float vmin = 1e30f, vmax = -1e30f;
    for (int i = blockIdx.x * 256 + threadIdx.x; i < NV_; i += MMB_ * 256) {
        float z = tv[3*i + 2];
        vmin = fminf(vmin, z);
        vmax = fmaxf(vmax, z);
    }
#pragma unroll
    for (int off = 32; off > 0; off >>= 1) {
        vmin = fminf(vmin, __shfl_down(vmin, off));
        vmax = fmaxf(vmax, __shfl_down(vmax, off));
    }
    __shared__ float smin[4], smax[4];
    const int lane = threadIdx.x & 63, w = threadIdx.x >> 6;
    if (lane == 0) { smin[w] = vmin; smax[w] = vmax; }
    __syncthreads();
    if (threadIdx.x == 0) {
        float m = fminf(fminf(smin[0], smin[1]), fminf(smin[2], smin[3]));
        float M = fmaxf(fmaxf(smax[0], smax[1]), fmaxf(smax[2], smax[3]));
        partial[blockIdx.x] = make_uint2(encf(M), encf(m));
    }
}

// Kernel 2: redundant 64-wide reduce of partials, then build
// face_attr[n*F+f] = {zval(v0), zval(v1), zval(v2), 0}. Table 2.55 MB.
__global__ __launch_bounds__(256) void table_kernel(
        const float* __restrict__ tv, const int* __restrict__ faces,
        const uint2* __restrict__ partial, f32x4* __restrict__ table) {
    __shared__ float s_zmax, s_inv;
    if (threadIdx.x < 64) {
        uint2 p = partial[threadIdx.x];            // MMB_ == 64 == wave width
        unsigned int eM = p.x, em = p.y;
#pragma unroll
        for (int off = 32; off > 0; off >>= 1) {
            eM = max(eM, (unsigned int)__shfl_down((int)eM, off));
            em = min(em, (unsigned int)__shfl_down((int)em, off));
        }
        if (threadIdx.x == 0) {
            float zmax = decf(eM);
            s_zmax = zmax;
            s_inv  = 1.0f / (zmax - decf(em));
        }
    }
    __syncthreads();
    const int f = blockIdx.x * 256 + threadIdx.x;
    if (f >= F_) return;
    const int n = blockIdx.y;
    const float zmax = s_zmax, inv = s_inv;
    const int v0 = faces[3*f], v1 = faces[3*f + 1], v2 = faces[3*f + 2];
    const float* base = tv + n * (V_ * 3);
    f32x4 o;
    o.x = (zmax - base[3*v0 + 2]) * inv;
    o.y = (zmax - base[3*v1 + 2]) * inv;
    o.z = (zmax - base[3*v2 + 2]) * inv;
    o.w = 0.0f;
    table[n * F_ + f] = o;
}

// Kernel 3: render, 4 pixels/thread.
//  - Streams use PLAIN cached loads: harness restores p2f/bary immediately
//    before launch, so they're L2/L3-warm; nt loads bypassed that and raised
//    FETCH_SIZE 34.5->50 MB (R6 evidence).
//  - Gathers are predicated but LOAD-ONLY in the branch body (attr defaults
//    to 0, FMA outside) so no waitcnt lands inside the branches and all 4
//    gathers stay in flight together. Invalid pixels: 0*bary = 0. R6's
//    load+FMA-in-branch serialized 8 gather latencies -> 41.6 us.
//  - nt store only (write-once, read by validator off the timed path).
__global__ __launch_bounds__(256) void render_kernel(
        const int*    __restrict__ p2f,    // (NPIX) int32
        const float*  __restrict__ bary,   // (NPIX,3) f32
        const f32x4*  __restrict__ table,  // (N*F) f32x4
        float*        __restrict__ out) {  // (NPIX) f32
    const int t = blockIdx.x * 256 + threadIdx.x;   // pixels 4t .. 4t+3
    const i32x4 pp  = ((const i32x4*)p2f)[t];
    const f32x4 ba0 = ((const f32x4*)bary)[3*t + 0];
    const f32x4 ba1 = ((const f32x4*)bary)[3*t + 1];
    const f32x4 ba2 = ((const f32x4*)bary)[3*t + 2];

    f32x4 a0 = {0.f, 0.f, 0.f, 0.f};
    f32x4 a1 = {0.f, 0.f, 0.f, 0.f};
    f32x4 a2 = {0.f, 0.f, 0.f, 0.f};
    f32x4 a3 = {0.f, 0.f, 0.f, 0.f};
    if (pp.x >= 0) a0 = table[pp.x];
    if (pp.y >= 0) a1 = table[pp.y];
    if (pp.z >= 0) a2 = table[pp.z];
    if (pp.w >= 0) a3 = table[pp.w];

    f32x4 o;
    o.x = ba0.x * a0.x + ba0.y * a0.y + ba0.z * a0.z;
    o.y = ba0.w * a1.x + ba1.x * a1.y + ba1.y * a1.z;
    o.z = ba1.z * a2.x + ba1.w * a2.y + ba2.x * a2.z;
    o.w = ba2.y * a3.x + ba2.z * a3.y + ba2.w * a3.z;
    __builtin_nontemporal_store(o, (f32x4*)out + t);
}

extern "C" void kernel_launch(void* const* d_in, const int* in_sizes, int n_in,
                              void* d_out, int out_size, void* d_ws, size_t ws_size,
                              hipStream_t stream) {
    const float* tv    = (const float*)d_in[0];  // f32 (N,V,3)
    const float* bary  = (const float*)d_in[1];  // f32 (N,H,W,1,3)
    const int*   faces = (const int*)d_in[2];    // int32 (F,3)
    const int*   p2f   = (const int*)d_in[3];    // int32 (N,H,W,1)
    float* outp = (float*)d_out;

    uint2* partial = (uint2*)d_ws;                     // 64 * 8 B
    f32x4* table   = (f32x4*)((char*)d_ws + 1024);     // 2.55 MB, 16B-aligned

    minmax_kernel<<<MMB_, 256, 0, stream>>>(tv, partial);
    dim3 tgrid((F_ + 255) / 256, N_);
    table_kernel<<<tgrid, 256, 0, stream>>>(tv, faces, partial, table);
    render_kernel<<<NPIX_ / 4 / 256, 256, 0, stream>>>(p2f, bary, table, outp);
}

// Round 8
// 122.054 us; speedup vs baseline: 1.1676x; 1.0002x over previous
//
#include <hip/hip_runtime.h>
#include <hip/hip_bf16.h>

#define N_    16
#define V_    5023
#define F_    9976
#define HW_   (512*512)
#define NV_   (N_*V_)      // 80368
#define NF_   (N_*F_)      // 159616
#define NPIX_ (N_*HW_)     // 4194304
#define MMB_  64           // minmax partial blocks

// native clang vectors — required by __builtin_nontemporal_* (HIP float4 is a struct)
typedef float f32x4 __attribute__((ext_vector_type(4)));
typedef int   i32x4 __attribute__((ext_vector_type(4)));

// ---- ordered-float <-> uint encoding (monotone over all finite floats) ----
__device__ __forceinline__ unsigned int encf(float f) {
    unsigned int b = __float_as_uint(f);
    return (b & 0x80000000u) ? ~b : (b | 0x80000000u);
}
__device__ __forceinline__ float decf(unsigned int e) {
    unsigned int b = (e & 0x80000000u) ? (e & 0x7FFFFFFFu) : ~e;
    return __uint_as_float(b);
}

// Kernel 1: per-block min/max partials over tv[:,:,2].
__global__ __launch_bounds__(256) void minmax_kernel(
        const float* __restrict__ tv, uint2* __restrict__ partial) {
    float vmin = 1e30f, vmax = -1e30f;
    for (int i = blockIdx.x * 256 + threadIdx.x; i < NV_; i += MMB_ * 256) {
        float z = tv[3*i + 2];
        vmin = fminf(vmin, z);
        vmax = fmaxf(vmax, z);
    }
#pragma unroll
    for (int off = 32; off > 0; off >>= 1) {
        vmin = fminf(vmin, __shfl_down(vmin, off));
        vmax = fmaxf(vmax, __shfl_down(vmax, off));
    }
    __shared__ float smin[4], smax[4];
    const int lane = threadIdx.x & 63, w = threadIdx.x >> 6;
    if (lane == 0) { smin[w] = vmin; smax[w] = vmax; }
    __syncthreads();
    if (threadIdx.x == 0) {
        float m = fminf(fminf(smin[0], smin[1]), fminf(smin[2], smin[3]));
        float M = fmaxf(fmaxf(smax[0], smax[1]), fmaxf(smax[2], smax[3]));
        partial[blockIdx.x] = make_uint2(encf(M), encf(m));
    }
}

// Kernel 2: redundant 64-wide reduce of partials, then build
// face_attr[n*F+f] = {zval(v0), zval(v1), zval(v2), 0}. Table 2.55 MB.
__global__ __launch_bounds__(256) void table_kernel(
        const float* __restrict__ tv, const int* __restrict__ faces,
        const uint2* __restrict__ partial, f32x4* __restrict__ table) {
    __shared__ float s_zmax, s_inv;
    if (threadIdx.x < 64) {
        uint2 p = partial[threadIdx.x];            // MMB_ == 64 == wave width
        unsigned int eM = p.x, em = p.y;
#pragma unroll
        for (int off = 32; off > 0; off >>= 1) {
            eM = max(eM, (unsigned int)__shfl_down((int)eM, off));
            em = min(em, (unsigned int)__shfl_down((int)em, off));
        }
        if (threadIdx.x == 0) {
            float zmax = decf(eM);
            s_zmax = zmax;
            s_inv  = 1.0f / (zmax - decf(em));
        }
    }
    __syncthreads();
    const int f = blockIdx.x * 256 + threadIdx.x;
    if (f >= F_) return;
    const int n = blockIdx.y;
    const float zmax = s_zmax, inv = s_inv;
    const int v0 = faces[3*f], v1 = faces[3*f + 1], v2 = faces[3*f + 2];
    const float* base = tv + n * (V_ * 3);
    f32x4 o;
    o.x = (zmax - base[3*v0 + 2]) * inv;
    o.y = (zmax - base[3*v1 + 2]) * inv;
    o.z = (zmax - base[3*v2 + 2]) * inv;
    o.w = 0.0f;
    table[n * F_ + f] = o;
}

// Kernel 3: render, 8 pixels/thread.
//  - Plain cached stream loads (inputs are L3-warm from the harness restore;
//    nt loads raised FETCH 34.5->50 MB in R6).
//  - Gathers predicated but LOAD-ONLY in the branch (attr=0 default, FMA
//    outside): no waitcnt inside branches, all 8 gathers in flight together.
//    (R6's regression was FMA-in-branch serialization, not 8-pix width.)
//  - nt store only.
__global__ __launch_bounds__(256) void render_kernel(
        const int*    __restrict__ p2f,    // (NPIX) int32
        const float*  __restrict__ bary,   // (NPIX,3) f32
        const f32x4*  __restrict__ table,  // (N*F) f32x4
        float*        __restrict__ out) {  // (NPIX) f32
    const int t = blockIdx.x * 256 + threadIdx.x;   // pixels 8t .. 8t+7
    const i32x4 pp0 = ((const i32x4*)p2f)[2*t + 0];
    const i32x4 pp1 = ((const i32x4*)p2f)[2*t + 1];
    const f32x4 ba0 = ((const f32x4*)bary)[6*t + 0];
    const f32x4 ba1 = ((const f32x4*)bary)[6*t + 1];
    const f32x4 ba2 = ((const f32x4*)bary)[6*t + 2];
    const f32x4 ba3 = ((const f32x4*)bary)[6*t + 3];
    const f32x4 ba4 = ((const f32x4*)bary)[6*t + 4];
    const f32x4 ba5 = ((const f32x4*)bary)[6*t + 5];

    f32x4 a0 = {0.f,0.f,0.f,0.f}, a1 = {0.f,0.f,0.f,0.f};
    f32x4 a2 = {0.f,0.f,0.f,0.f}, a3 = {0.f,0.f,0.f,0.f};
    f32x4 a4 = {0.f,0.f,0.f,0.f}, a5 = {0.f,0.f,0.f,0.f};
    f32x4 a6 = {0.f,0.f,0.f,0.f}, a7 = {0.f,0.f,0.f,0.f};
    if (pp0.x >= 0) a0 = table[pp0.x];
    if (pp0.y >= 0) a1 = table[pp0.y];
    if (pp0.z >= 0) a2 = table[pp0.z];
    if (pp0.w >= 0) a3 = table[pp0.w];
    if (pp1.x >= 0) a4 = table[pp1.x];
    if (pp1.y >= 0) a5 = table[pp1.y];
    if (pp1.z >= 0) a6 = table[pp1.z];
    if (pp1.w >= 0) a7 = table[pp1.w];

    f32x4 o0, o1;
    o0.x = ba0.x * a0.x + ba0.y * a0.y + ba0.z * a0.z;
    o0.y = ba0.w * a1.x + ba1.x * a1.y + ba1.y * a1.z;
    o0.z = ba1.z * a2.x + ba1.w * a2.y + ba2.x * a2.z;
    o0.w = ba2.y * a3.x + ba2.z * a3.y + ba2.w * a3.z;
    o1.x = ba3.x * a4.x + ba3.y * a4.y + ba3.z * a4.z;
    o1.y = ba3.w * a5.x + ba4.x * a5.y + ba4.y * a5.z;
    o1.z = ba4.z * a6.x + ba4.w * a6.y + ba5.x * a6.z;
    o1.w = ba5.y * a7.x + ba5.z * a7.y + ba5.w * a7.z;
    __builtin_nontemporal_store(o0, (f32x4*)out + 2*t + 0);
    __builtin_nontemporal_store(o1, (f32x4*)out + 2*t + 1);
}

extern "C" void kernel_launch(void* const* d_in, const int* in_sizes, int n_in,
                              void* d_out, int out_size, void* d_ws, size_t ws_size,
                              hipStream_t stream) {
    const float* tv    = (const float*)d_in[0];  // f32 (N,V,3)
    const float* bary  = (const float*)d_in[1];  // f32 (N,H,W,1,3)
    const int*   faces = (const int*)d_in[2];    // int32 (F,3)
    const int*   p2f   = (const int*)d_in[3];    // int32 (N,H,W,1)
    float* outp = (float*)d_out;

    uint2* partial = (uint2*)d_ws;                     // 64 * 8 B
    f32x4* table   = (f32x4*)((char*)d_ws + 1024);     // 2.55 MB, 16B-aligned

    minmax_kernel<<<MMB_, 256, 0, stream>>>(tv, partial);
    dim3 tgrid((F_ + 255) / 256, N_);
    table_kernel<<<tgrid, 256, 0, stream>>>(tv, faces, partial, table);
    render_kernel<<<NPIX_ / 8 / 256, 256, 0, stream>>>(p2f, bary, table, outp);
}

// Round 9
// 117.895 us; speedup vs baseline: 1.2088x; 1.0353x over previous
//
#include <hip/hip_runtime.h>
#include <hip/hip_bf16.h>

#define N_    16
#define V_    5023
#define F_    9976
#define HW_   (512*512)
#define NV_   (N_*V_)      // 80368
#define NF_   (N_*F_)      // 159616
#define NPIX_ (N_*HW_)     // 4194304
#define MMB_  64           // minmax partial blocks
#define TBLK_ 39           // ceil(F/256) table blocks per n
#define SETUP_BLOCKS (TBLK_*N_ + MMB_)   // 624 + 64 = 688

// native clang vectors — required by __builtin_nontemporal_* (HIP float4 is a struct)
typedef float f32x4 __attribute__((ext_vector_type(4)));
typedef int   i32x4 __attribute__((ext_vector_type(4)));

// ---- ordered-float <-> uint encoding (monotone over all finite floats) ----
__device__ __forceinline__ unsigned int encf(float f) {
    unsigned int b = __float_as_uint(f);
    return (b & 0x80000000u) ? ~b : (b | 0x80000000u);
}
__device__ __forceinline__ float decf(unsigned int e) {
    unsigned int b = (e & 0x80000000u) ? (e & 0x7FFFFFFFu) : ~e;
    return __uint_as_float(b);
}

// Kernel 1 (fused setup): blocks [0,624) build the RAW-z face table
// table[n*F+f] = {z(v0), z(v1), z(v2), 0}; blocks [624,688) compute min/max
// partials of tv[:,:,2]. The two roles are independent (raw z needs no
// normalization), so the old minmax->table serialization disappears.
// Render applies the affine: out = (zmax - dot(b, z_raw)) * inv, since
// sum(bary)=1 (fp32-normalized; identity error ~1e-7, << 3.9e-3 absmax).
__global__ __launch_bounds__(256) void setup_kernel(
        const float* __restrict__ tv, const int* __restrict__ faces,
        uint2* __restrict__ partial, f32x4* __restrict__ table) {
    const int bid = blockIdx.x;
    if (bid < TBLK_ * N_) {
        const int n = bid / TBLK_;
        const int f = (bid % TBLK_) * 256 + threadIdx.x;
        if (f >= F_) return;
        const int v0 = faces[3*f], v1 = faces[3*f + 1], v2 = faces[3*f + 2];
        const float* base = tv + n * (V_ * 3);
        f32x4 o;
        o.x = base[3*v0 + 2];
        o.y = base[3*v1 + 2];
        o.z = base[3*v2 + 2];
        o.w = 0.0f;
        table[n * F_ + f] = o;
    } else {
        const int mb = bid - TBLK_ * N_;          // 0..63
        float vmin = 1e30f, vmax = -1e30f;
        for (int i = mb * 256 + threadIdx.x; i < NV_; i += MMB_ * 256) {
            float z = tv[3*i + 2];
            vmin = fminf(vmin, z);
            vmax = fmaxf(vmax, z);
        }
#pragma unroll
        for (int off = 32; off > 0; off >>= 1) {
            vmin = fminf(vmin, __shfl_down(vmin, off));
            vmax = fmaxf(vmax, __shfl_down(vmax, off));
        }
        __shared__ float smin[4], smax[4];
        const int lane = threadIdx.x & 63, w = threadIdx.x >> 6;
        if (lane == 0) { smin[w] = vmin; smax[w] = vmax; }
        __syncthreads();
        if (threadIdx.x == 0) {
            float m = fminf(fminf(smin[0], smin[1]), fminf(smin[2], smin[3]));
            float M = fmaxf(fmaxf(smax[0], smax[1]), fmaxf(smax[2], smax[3]));
            partial[mb] = make_uint2(encf(M), encf(m));
        }
    }
}

// Kernel 2: render, 4 pixels/thread.
//  - Per-block: wave 0 reduces the 64 minmax partials -> (zmax, inv) in LDS.
//  - Plain cached stream loads (inputs L3-warm from harness restore; nt loads
//    raised FETCH 34.5->50 MB in R6). nt store only.
//  - Gathers predicated LOAD-ONLY (no waitcnt inside branch; all 4 in
//    flight). Invalid pixels forced to 0 by the final select.
__global__ __launch_bounds__(256) void render_kernel(
        const int*    __restrict__ p2f,    // (NPIX) int32
        const float*  __restrict__ bary,   // (NPIX,3) f32
        const f32x4*  __restrict__ table,  // (N*F) raw-z f32x4
        const uint2*  __restrict__ partial,
        float*        __restrict__ out) {  // (NPIX) f32
    __shared__ float s_zmax, s_inv;
    if (threadIdx.x < 64) {
        uint2 p = partial[threadIdx.x];            // MMB_ == 64 == wave width
        unsigned int eM = p.x, em = p.y;
#pragma unroll
        for (int off = 32; off > 0; off >>= 1) {
            eM = max(eM, (unsigned int)__shfl_down((int)eM, off));
            em = min(em, (unsigned int)__shfl_down((int)em, off));
        }
        if (threadIdx.x == 0) {
            float zmax = decf(eM);
            s_zmax = zmax;
            s_inv  = 1.0f / (zmax - decf(em));
        }
    }
    __syncthreads();
    const float zmax = s_zmax, inv = s_inv;

    const int t = blockIdx.x * 256 + threadIdx.x;   // pixels 4t .. 4t+3
    const i32x4 pp  = ((const i32x4*)p2f)[t];
    const f32x4 ba0 = ((const f32x4*)bary)[3*t + 0];
    const f32x4 ba1 = ((const f32x4*)bary)[3*t + 1];
    const f32x4 ba2 = ((const f32x4*)bary)[3*t + 2];

    f32x4 a0 = {0.f,0.f,0.f,0.f}, a1 = {0.f,0.f,0.f,0.f};
    f32x4 a2 = {0.f,0.f,0.f,0.f}, a3 = {0.f,0.f,0.f,0.f};
    if (pp.x >= 0) a0 = table[pp.x];
    if (pp.y >= 0) a1 = table[pp.y];
    if (pp.z >= 0) a2 = table[pp.z];
    if (pp.w >= 0) a3 = table[pp.w];

    f32x4 o;
    o.x = (pp.x >= 0) ? (zmax - (ba0.x*a0.x + ba0.y*a0.y + ba0.z*a0.z)) * inv : 0.0f;
    o.y = (pp.y >= 0) ? (zmax - (ba0.w*a1.x + ba1.x*a1.y + ba1.y*a1.z)) * inv : 0.0f;
    o.z = (pp.z >= 0) ? (zmax - (ba1.z*a2.x + ba1.w*a2.y + ba2.x*a2.z)) * inv : 0.0f;
    o.w = (pp.w >= 0) ? (zmax - (ba2.y*a3.x + ba2.z*a3.y + ba2.w*a3.z)) * inv : 0.0f;
    __builtin_nontemporal_store(o, (f32x4*)out + t);
}

extern "C" void kernel_launch(void* const* d_in, const int* in_sizes, int n_in,
                              void* d_out, int out_size, void* d_ws, size_t ws_size,
                              hipStream_t stream) {
    const float* tv    = (const float*)d_in[0];  // f32 (N,V,3)
    const float* bary  = (const float*)d_in[1];  // f32 (N,H,W,1,3)
    const int*   faces = (const int*)d_in[2];    // int32 (F,3)
    const int*   p2f   = (const int*)d_in[3];    // int32 (N,H,W,1)
    float* outp = (float*)d_out;

    uint2* partial = (uint2*)d_ws;                     // 64 * 8 B
    f32x4* table   = (f32x4*)((char*)d_ws + 1024);     // 2.55 MB, 16B-aligned

    setup_kernel<<<SETUP_BLOCKS, 256, 0, stream>>>(tv, faces, partial, table);
    render_kernel<<<NPIX_ / 4 / 256, 256, 0, stream>>>(p2f, bary, table, partial, outp);
}